// Round 15
// baseline (995.523 us; speedup 1.0000x reference)
//
#include <hip/hip_runtime.h>
#include <hip/hip_bf16.h>
#include <stdint.h>
#include <stddef.h>

// DecoderStepLayer R14-M: MEASUREMENT ROUND #3. R14 production structure
// (167.5us verified) with rep counts on exactly two suspects, in separable
// duration bands: g_ln x100 (3 calls; top-5 -> direct unit) and g_attn x4
// (2 calls; unit via total-time algebra). All other kernels production.

#define DEV __device__ __forceinline__

typedef __attribute__((ext_vector_type(8))) short bf16x8;
typedef __attribute__((ext_vector_type(4))) short bf16x4;
typedef __attribute__((ext_vector_type(4))) float f32x4;

DEV unsigned short f2b(float f){
  union { __hip_bfloat16 h; unsigned short u; } cv;
  cv.h = __float2bfloat16(f);
  return cv.u;
}
DEV float b2f(unsigned short u){
  union { unsigned int i; float f; } cv;
  cv.i = ((unsigned int)u) << 16;
  return cv.f;
}
DEV f32x4 mfma16(bf16x8 a, bf16x8 b, f32x4 c){
  return __builtin_amdgcn_mfma_f32_16x16x32_bf16(a, b, c, 0, 0, 0);
}

// ---------------------------------------------------------------------------
// qA: Qpart[h][ks][b][k] = sum_{d' in 128-slice} src[b,d']*wq[h,d',k]
__global__ __launch_bounds__(256) void g_qA(const float* __restrict__ src,
    const float* __restrict__ wq, float* __restrict__ Qpart){
  int ks = blockIdx.x, h = blockIdx.y;
  int k0b = ks*128;
  __shared__ unsigned short lt[2][64*40];
  int t = threadIdx.x, lane = t & 63, w = t >> 6;
  int k_loc = t >> 3, n_off = (t & 7)*8;
  const float* apf = src + (size_t)(lane & 15)*1024 + (lane >> 4)*8 + k0b;
  const float* Wb = wq + (size_t)h*65536;
  f32x4 acc = {0.f,0.f,0.f,0.f};
  float4 x0, x1;
  auto LD = [&](int c){
    const float* wp = Wb + (size_t)(k0b + c*32 + k_loc)*64 + n_off;
    x0 = *(const float4*)wp;
    x1 = *(const float4*)(wp + 4);
  };
  auto ST = [&](int buf){
    unsigned short* p = &lt[buf][0];
    p[(n_off+0)*40 + k_loc] = f2b(x0.x);
    p[(n_off+1)*40 + k_loc] = f2b(x0.y);
    p[(n_off+2)*40 + k_loc] = f2b(x0.z);
    p[(n_off+3)*40 + k_loc] = f2b(x0.w);
    p[(n_off+4)*40 + k_loc] = f2b(x1.x);
    p[(n_off+5)*40 + k_loc] = f2b(x1.y);
    p[(n_off+6)*40 + k_loc] = f2b(x1.z);
    p[(n_off+7)*40 + k_loc] = f2b(x1.w);
  };
  LD(0); ST(0);
  for(int c=0; c<4; ++c){
    if(c+1 < 4) LD(c+1);
    __syncthreads();
    float4 a0 = *(const float4*)(apf + c*32);
    float4 a1 = *(const float4*)(apf + c*32 + 4);
    bf16x8 af;
    af[0]=(short)f2b(a0.x); af[1]=(short)f2b(a0.y);
    af[2]=(short)f2b(a0.z); af[3]=(short)f2b(a0.w);
    af[4]=(short)f2b(a1.x); af[5]=(short)f2b(a1.y);
    af[6]=(short)f2b(a1.z); af[7]=(short)f2b(a1.w);
    bf16x8 bv = *(const bf16x8*)&lt[c&1][(w*16 + (lane & 15))*40 + (lane >> 4)*8];
    acc = mfma16(af, bv, acc);
    if(c+1 < 4) ST((c+1)&1);
  }
  int col = w*16 + (lane & 15);
  int r0 = (lane >> 4)*4;
  #pragma unroll
  for(int i=0;i<4;++i)
    Qpart[ ((size_t)(h*8 + ks)*16 + r0 + i)*64 + col ] = acc[i];
}

// ---------------------------------------------------------------------------
// qB: qpb[b][h][d] = bf16( sum_k wk[h,d,k] * 0.125*sum_ks Qpart[h][ks][b][k] )
__global__ __launch_bounds__(256) void g_qB(const float* __restrict__ wk,
    const float* __restrict__ Qpart, unsigned short* __restrict__ qpb){
  int dt = blockIdx.x, h = blockIdx.y;
  int t = threadIdx.x;
  __shared__ float Qs[1024];
  #pragma unroll
  for(int i=0;i<4;++i){
    int idx = i*256 + t;
    float s = 0.f;
    #pragma unroll
    for(int ks=0; ks<8; ++ks)
      s += Qpart[((size_t)h<<13) + (ks<<10) + idx];
    Qs[idx] = s * 0.125f;
  }
  __syncthreads();
  int d_loc = t & 63, bg = t >> 6;
  const float* wr = wk + (size_t)h*65536 + (size_t)(dt*64 + d_loc)*64;
  float acc[4] = {0.f,0.f,0.f,0.f};
  #pragma unroll
  for(int k4=0; k4<16; ++k4){
    float4 w4 = *(const float4*)(wr + k4*4);
    #pragma unroll
    for(int i=0;i<4;++i){
      const float* q = &Qs[(bg*4+i)*64 + k4*4];
      acc[i] += w4.x*q[0] + w4.y*q[1] + w4.z*q[2] + w4.w*q[3];
    }
  }
  #pragma unroll
  for(int i=0;i<4;++i)
    qpb[ ((size_t)(bg*4+i)*16 + h)*1024 + dt*64 + d_loc ] = f2b(acc[i]);
}

// ---------------------------------------------------------------------------
// attn: grid 512 = (ns 32, b 16). Block = 64 rows, 4 chunks of 16. rep-able.
__global__ __launch_bounds__(256) void g_attn(const float* __restrict__ kvsrc,
    const float* __restrict__ decrow, const unsigned short* __restrict__ qpb,
    float* __restrict__ scr, unsigned short* __restrict__ partb,
    float* __restrict__ msum, int lsrc, int rep){
  int u = blockIdx.x, ns = u & 31, b = u >> 5;
  int t = threadIdx.x, lane = t & 63, w = t >> 6;
  int r = lane & 15, hi = lane >> 4;
  int slice0 = ns*64;

  __shared__ unsigned short lt[1024*20];
  __shared__ float red[1024];
  __shared__ unsigned short p_lds[16*40];
  __shared__ float f_lds[16];

  #pragma unroll 1
  for(int rp=0; rp<rep; ++rp){
    __syncthreads();
    float4 ld[16];
    auto ISSUE = [&](int c){
      int row = slice0 + c*16 + r;
      const float* rpp = (row < lsrc) ? kvsrc + ((size_t)b*lsrc + row)*1024
                                      : decrow + (size_t)b*1024;
      rpp += w*256 + hi*8;
      #pragma unroll
      for(int kk=0; kk<8; ++kk){
        ld[kk*2+0] = *(const float4*)(rpp + kk*32);
        ld[kk*2+1] = *(const float4*)(rpp + kk*32 + 4);
      }
    };

    ISSUE(0);
    for(int i=t; i<16*40; i+=256) p_lds[i] = 0;

    bf16x8 qf[8];
    {
      const unsigned short* qp = qpb + ((size_t)b*16 + r)*1024 + w*256 + hi*8;
      #pragma unroll
      for(int kk=0;kk<8;++kk) qf[kk] = *(const bf16x8*)(qp + kk*32);
    }

    f32x4 acc[16];
    #pragma unroll
    for(int i=0;i<16;++i) acc[i] = (f32x4){0.f,0.f,0.f,0.f};
    float m_run = -1e30f, s_run = 0.f;

    __syncthreads();
    for(int c=0; c<4; ++c){
      f32x4 s_acc = {0.f,0.f,0.f,0.f};
      int colw = r ^ ((hi & 1) << 3);
      #pragma unroll
      for(int kk=0; kk<8; ++kk){
        float4 a0 = ld[kk*2], a1 = ld[kk*2+1];
        bf16x8 v;
        v[0]=(short)f2b(a0.x); v[1]=(short)f2b(a0.y);
        v[2]=(short)f2b(a0.z); v[3]=(short)f2b(a0.w);
        v[4]=(short)f2b(a1.x); v[5]=(short)f2b(a1.y);
        v[6]=(short)f2b(a1.z); v[7]=(short)f2b(a1.w);
        unsigned short* pt = &lt[(w*256 + hi*8 + kk*32)*20 + colw];
        #pragma unroll
        for(int j=0;j<8;++j) pt[j*20] = (unsigned short)v[j];
        s_acc = mfma16(v, qf[kk], s_acc);
      }
      if(c < 3) ISSUE(c+1);
      *(f32x4*)&red[t*4] = s_acc;
      __syncthreads();                     // (A)

      f32x4 ss = *(const f32x4*)&red[(0*64+lane)*4];
      ss += *(const f32x4*)&red[(1*64+lane)*4];
      ss += *(const f32x4*)&red[(2*64+lane)*4];
      ss += *(const f32x4*)&red[(3*64+lane)*4];
      float sf[4] = {ss[0], ss[1], ss[2], ss[3]};
      float mc = fmaxf(fmaxf(sf[0],sf[1]), fmaxf(sf[2],sf[3]));
      mc = fmaxf(mc, __shfl_xor(mc, 16));
      mc = fmaxf(mc, __shfl_xor(mc, 32));
      float nm = fmaxf(m_run, mc);
      float fch = __expf(m_run - nm);
      float pvv[4]; float ps = 0.f;
      #pragma unroll
      for(int i=0;i<4;++i){ pvv[i] = __expf(sf[i]-nm); ps += pvv[i]; }
      ps += __shfl_xor(ps, 16);
      ps += __shfl_xor(ps, 32);
      s_run = s_run*fch + ps;
      m_run = nm;
      if(w == 0){
        #pragma unroll
        for(int i=0;i<4;++i) p_lds[r*40 + hi*4 + i] = f2b(pvv[i]);
        if(hi == 0) f_lds[r] = fch;
        float* sp = scr + ((size_t)b*16 + r)*2048 + slice0 + c*16 + hi*4;
        *(float4*)sp = (float4){sf[0], sf[1], sf[2], sf[3]};
      }
      __syncthreads();                     // (B)

      f32x4 fv = *(const f32x4*)&f_lds[hi*4];
      bf16x8 pa = *(const bf16x8*)&p_lds[r*40 + hi*8];
      #pragma unroll
      for(int dc=0; dc<16; ++dc){
        acc[dc] *= fv;
        int d = w*256 + dc*16 + r;
        int col0 = (((hi & 1) ^ ((r >> 3) & 1)) << 3);
        bf16x4 blo = *(const bf16x4*)&lt[d*20 + col0];
        bf16x4 bhi = *(const bf16x4*)&lt[d*20 + col0 + 4];
        bf16x8 bv;
        bv[0]=blo[0]; bv[1]=blo[1]; bv[2]=blo[2]; bv[3]=blo[3];
        bv[4]=bhi[0]; bv[5]=bhi[1]; bv[6]=bhi[2]; bv[7]=bhi[3];
        acc[dc] = mfma16(pa, bv, acc[dc]);
      }
      __syncthreads();                     // (C)
    }
    unsigned short* pl = lt;
    #pragma unroll
    for(int dc=0; dc<16; ++dc)
      #pragma unroll
      for(int i=0;i<4;++i)
        pl[(hi*4+i)*1024 + w*256 + dc*16 + r] = f2b(acc[dc][i]);
    __syncthreads();
    {
      const uint4* s4 = (const uint4*)pl;
      uint4* d4 = (uint4*)(partb + (((size_t)b*32 + ns)*16)*1024);
      #pragma unroll
      for(int j=0;j<8;++j) d4[t + j*256] = s4[t + j*256];
    }
    if(w==0 && hi==0){
      msum[(((size_t)b*32 + ns)*16 + r)*2 + 0] = m_run;
      msum[(((size_t)b*32 + ns)*16 + r)*2 + 1] = s_run;
    }
  }
}

// ---------------------------------------------------------------------------
// comb: grid (dq 4, bh 256), blk 256. 32-slice combine + probs + bf16 ctx.
__global__ __launch_bounds__(256) void g_comb(const float* __restrict__ msum,
    const float* __restrict__ scr, const unsigned short* __restrict__ partb,
    float* __restrict__ attn_out, unsigned short* __restrict__ ctxb){
  int dq = blockIdx.x, bh = blockIdx.y, b = bh >> 4, h = bh & 15;
  int t = threadIdx.x;
  __shared__ float e_lds[32];
  __shared__ float Mi[2];
  if(t < 32){
    float2 ms = *(const float2*)&msum[(((size_t)b*32 + t)*16 + h)*2];
    float M = ms.x;
    #pragma unroll
    for(int o=1; o<32; o<<=1) M = fmaxf(M, __shfl_xor(M, o));
    float e = __expf(ms.x - M)*ms.y;
    float S = e;
    #pragma unroll
    for(int o=1; o<32; o<<=1) S += __shfl_xor(S, o);
    e_lds[t] = __expf(ms.x - M)/S;
    if(t == 0){ Mi[0] = M; Mi[1] = 1.f/S; }
  }
  __syncthreads();
  float M = Mi[0], inv = Mi[1];
  const float* sp = scr + (size_t)bh*2048 + dq*512;
  float* po = attn_out + (size_t)bh*2048 + dq*512;
  po[t]     = __expf(sp[t]     - M)*inv;
  po[t+256] = __expf(sp[t+256] - M)*inv;
  int d = dq*256 + t;
  const unsigned short* pb0 = partb + ((size_t)b*32*16 + h)*1024 + d;
  float acc = 0.f;
  #pragma unroll 8
  for(int ns=0; ns<32; ++ns)
    acc += e_lds[ns]*b2f(pb0[(size_t)ns*16384]);
  ctxb[(size_t)bh*1024 + d] = f2b(acc);
}

// ---------------------------------------------------------------------------
// vproj: opart[h][ks][b][v] = sum_{d in 128-slice} ctxb[b][h][d]*wv[h][d][v]
__global__ __launch_bounds__(256) void g_vproj(const float* __restrict__ wv,
    const unsigned short* __restrict__ ctxb, float* __restrict__ opart){
  int ks = blockIdx.x, h = blockIdx.y;
  int k0b = ks*128;
  __shared__ unsigned short lt[2][64*40];
  int t = threadIdx.x, lane = t & 63, w = t >> 6;
  int k_loc = t >> 3, n_off = (t & 7)*8;
  const unsigned short* apb = ctxb + (size_t)(lane & 15)*16384 + (size_t)h*1024
                              + (lane >> 4)*8 + k0b;
  const float* Wb = wv + (size_t)h*65536;
  f32x4 acc = {0.f,0.f,0.f,0.f};
  float4 x0, x1;
  auto LD = [&](int c){
    const float* wp = Wb + (size_t)(k0b + c*32 + k_loc)*64 + n_off;
    x0 = *(const float4*)wp;
    x1 = *(const float4*)(wp + 4);
  };
  auto ST = [&](int buf){
    unsigned short* p = &lt[buf][0];
    p[(n_off+0)*40 + k_loc] = f2b(x0.x);
    p[(n_off+1)*40 + k_loc] = f2b(x0.y);
    p[(n_off+2)*40 + k_loc] = f2b(x0.z);
    p[(n_off+3)*40 + k_loc] = f2b(x0.w);
    p[(n_off+4)*40 + k_loc] = f2b(x1.x);
    p[(n_off+5)*40 + k_loc] = f2b(x1.y);
    p[(n_off+6)*40 + k_loc] = f2b(x1.z);
    p[(n_off+7)*40 + k_loc] = f2b(x1.w);
  };
  LD(0); ST(0);
  for(int c=0; c<4; ++c){
    if(c+1 < 4) LD(c+1);
    __syncthreads();
    bf16x8 af = *(const bf16x8*)(apb + c*32);
    bf16x8 bv = *(const bf16x8*)&lt[c&1][(w*16 + (lane & 15))*40 + (lane >> 4)*8];
    acc = mfma16(af, bv, acc);
    if(c+1 < 4) ST((c+1)&1);
  }
  int col = w*16 + (lane & 15);
  int r0 = (lane >> 4)*4;
  #pragma unroll
  for(int i=0;i<4;++i)
    opart[ ((size_t)(h*8 + ks)*16 + r0 + i)*64 + col ] = acc[i];
}

// ---------------------------------------------------------------------------
// skgo: wo-GEMM with ovred folded into the A-build. grid (nt 16, h 16).
__global__ __launch_bounds__(256) void g_skgo(const float* __restrict__ wo,
    const float* __restrict__ opart, float* __restrict__ gpart){
  const int N = 1024;
  int nt = blockIdx.x, h = blockIdx.y;
  int n0 = nt*64, k0b = h*64;
  __shared__ unsigned short lt[2][64*40];
  __shared__ float obs[1024];
  int t = threadIdx.x, lane = t & 63, w = t >> 6;
  int k_loc = t >> 3, n_off = (t & 7)*8;
  {
    const float* base = opart + (size_t)h*8*16*64;
    int o = t*4, b = o >> 6, v = o & 63;
    float4 s = {0.f,0.f,0.f,0.f};
    #pragma unroll
    for(int ksl=0; ksl<8; ++ksl){
      float4 p = *(const float4*)(base + (size_t)(ksl*16 + b)*64 + v);
      s.x+=p.x; s.y+=p.y; s.z+=p.z; s.w+=p.w;
    }
    *(float4*)&obs[o] = s;
  }
  f32x4 acc = {0.f,0.f,0.f,0.f};
  float4 x0, x1;
  auto LD = [&](int c){
    const float* wp = wo + (size_t)(k0b + c*32 + k_loc)*N + n0 + n_off;
    x0 = *(const float4*)wp;
    x1 = *(const float4*)(wp + 4);
  };
  auto ST = [&](int buf){
    unsigned short* p = &lt[buf][0];
    p[(n_off+0)*40 + k_loc] = f2b(x0.x);
    p[(n_off+1)*40 + k_loc] = f2b(x0.y);
    p[(n_off+2)*40 + k_loc] = f2b(x0.z);
    p[(n_off+3)*40 + k_loc] = f2b(x0.w);
    p[(n_off+4)*40 + k_loc] = f2b(x1.x);
    p[(n_off+5)*40 + k_loc] = f2b(x1.y);
    p[(n_off+6)*40 + k_loc] = f2b(x1.z);
    p[(n_off+7)*40 + k_loc] = f2b(x1.w);
  };
  LD(0); ST(0);
  int arow = lane & 15, akof = (lane >> 4)*8;
  for(int c=0; c<2; ++c){
    if(c+1 < 2) LD(c+1);
    __syncthreads();
    const float* ap = &obs[arow*64 + c*32 + akof];
    bf16x8 af;
    af[0]=(short)f2b(ap[0]); af[1]=(short)f2b(ap[1]);
    af[2]=(short)f2b(ap[2]); af[3]=(short)f2b(ap[3]);
    af[4]=(short)f2b(ap[4]); af[5]=(short)f2b(ap[5]);
    af[6]=(short)f2b(ap[6]); af[7]=(short)f2b(ap[7]);
    bf16x8 bv = *(const bf16x8*)&lt[c&1][(w*16 + (lane & 15))*40 + (lane >> 4)*8];
    acc = mfma16(af, bv, acc);
    if(c+1 < 2) ST((c+1)&1);
  }
  int col = n0 + w*16 + (lane & 15);
  int r0 = (lane >> 4)*4;
  #pragma unroll
  for(int i=0;i<4;++i)
    gpart[ ((size_t)h*16 + r0 + i)*(size_t)N + col ] = acc[i];
}

// ---------------------------------------------------------------------------
// LN( sum_ks parts + bias + resid ) * g + bb -> xout [+ bf16]. grid 16. rep-able.
__global__ __launch_bounds__(256) void g_ln(const float* __restrict__ parts, int KS,
    const float* __restrict__ bias, const float* __restrict__ resid,
    const float* __restrict__ g, const float* __restrict__ bb,
    float* __restrict__ xout, unsigned short* __restrict__ xb16, int rep){
  int b = blockIdx.x, t = threadIdx.x;
  __shared__ float red[256];
  #pragma unroll 1
  for(int rp=0; rp<rep; ++rp){
    __syncthreads();
    const float4* bias4  = (const float4*)bias;
    const float4* resid4 = (const float4*)resid + (size_t)b*256;
    const float4* parts4 = (const float4*)parts;
    float4 s = bias4[t];
    { float4 rr = resid4[t]; s.x+=rr.x; s.y+=rr.y; s.z+=rr.z; s.w+=rr.w; }
    #pragma unroll 4
    for(int k=0;k<KS;++k){
      float4 pp = parts4[((size_t)k*16 + b)*256 + t];
      s.x+=pp.x; s.y+=pp.y; s.z+=pp.z; s.w+=pp.w;
    }
    red[t] = s.x+s.y+s.z+s.w; __syncthreads();
    for(int off=128; off>0; off>>=1){ if(t<off) red[t]+=red[t+off]; __syncthreads(); }
    float mean = red[0]*(1.f/1024.f); __syncthreads();
    float dx=s.x-mean, dy=s.y-mean, dz=s.z-mean, dw=s.w-mean;
    red[t] = dx*dx+dy*dy+dz*dz+dw*dw; __syncthreads();
    for(int off=128; off>0; off>>=1){ if(t<off) red[t]+=red[t+off]; __syncthreads(); }
    float rstd = rsqrtf(red[0]*(1.f/1024.f) + 1e-5f);
    float4 g4 = ((const float4*)g)[t], b4 = ((const float4*)bb)[t];
    float4 y;
    y.x = dx*rstd*g4.x + b4.x;
    y.y = dy*rstd*g4.y + b4.y;
    y.z = dz*rstd*g4.z + b4.z;
    y.w = dw*rstd*g4.w + b4.w;
    if(xout) ((float4*)xout)[(size_t)b*256 + t] = y;
    if(xb16){
      ushort4 uu;
      uu.x = f2b(y.x); uu.y = f2b(y.y); uu.z = f2b(y.z); uu.w = f2b(y.w);
      ((ushort4*)xb16)[(size_t)b*256 + t] = uu;
    }
  }
}

// ---------------------------------------------------------------------------
// skinny GEMM: part[ks,b,n] = A[16,Kslice] @ W[Kslice,N]   (A bf16)
__global__ __launch_bounds__(256) void g_skg(const float* __restrict__ W,
    const unsigned short* __restrict__ A, float* __restrict__ part,
    int N, int K, int KS){
  int nt = blockIdx.x, ks = blockIdx.y;
  int Ksl = K / KS, k0b = ks * Ksl, n0 = nt*64;
  int nc = Ksl >> 5;
  __shared__ unsigned short lt[2][64*40];
  int t = threadIdx.x, lane = t & 63, w = t >> 6;
  int k_loc = t >> 3, n_off = (t & 7)*8;
  const unsigned short* apb = A + (size_t)(lane & 15)*K + (lane >> 4)*8 + k0b;
  f32x4 acc = {0.f,0.f,0.f,0.f};
  float4 x0, x1;
  auto LD = [&](int c){
    const float* wp = W + (size_t)(k0b + c*32 + k_loc)*N + n0 + n_off;
    x0 = *(const float4*)wp;
    x1 = *(const float4*)(wp + 4);
  };
  auto ST = [&](int buf){
    unsigned short* p = &lt[buf][0];
    p[(n_off+0)*40 + k_loc] = f2b(x0.x);
    p[(n_off+1)*40 + k_loc] = f2b(x0.y);
    p[(n_off+2)*40 + k_loc] = f2b(x0.z);
    p[(n_off+3)*40 + k_loc] = f2b(x0.w);
    p[(n_off+4)*40 + k_loc] = f2b(x1.x);
    p[(n_off+5)*40 + k_loc] = f2b(x1.y);
    p[(n_off+6)*40 + k_loc] = f2b(x1.z);
    p[(n_off+7)*40 + k_loc] = f2b(x1.w);
  };
  LD(0); ST(0);
  for(int c=0; c<nc; ++c){
    if(c+1 < nc) LD(c+1);
    __syncthreads();
    bf16x8 af = *(const bf16x8*)(apb + c*32);
    bf16x8 bv = *(const bf16x8*)&lt[c&1][(w*16 + (lane & 15))*40 + (lane >> 4)*8];
    acc = mfma16(af, bv, acc);
    if(c+1 < nc) ST((c+1)&1);
  }
  int col = n0 + w*16 + (lane & 15);
  int r0 = (lane >> 4)*4;
  #pragma unroll
  for(int i=0;i<4;++i)
    part[ ((size_t)ks*16 + r0 + i)*(size_t)N + col ] = acc[i];
}

// ---------------------------------------------------------------------------
// skgf: FFN w2 GEMM with A = relu(sum_p fpart + b1) built in-register.
__global__ __launch_bounds__(256) void g_skgf(const float* __restrict__ W,
    const float* __restrict__ fpart, const float* __restrict__ b1,
    float* __restrict__ part){
  const int N = 1024, K = 4096, KS = 32;
  int nt = blockIdx.x, ks = blockIdx.y;
  int Ksl = K / KS, k0b = ks * Ksl, n0 = nt*64;
  int nc = Ksl >> 5;
  __shared__ unsigned short lt[2][64*40];
  int t = threadIdx.x, lane = t & 63, w = t >> 6;
  int k_loc = t >> 3, n_off = (t & 7)*8;
  int arow = lane & 15, akof = (lane >> 4)*8;
  f32x4 acc = {0.f,0.f,0.f,0.f};
  float4 x0, x1;
  auto LD = [&](int c){
    const float* wp = W + (size_t)(k0b + c*32 + k_loc)*N + n0 + n_off;
    x0 = *(const float4*)wp;
    x1 = *(const float4*)(wp + 4);
  };
  auto ST = [&](int buf){
    unsigned short* p = &lt[buf][0];
    p[(n_off+0)*40 + k_loc] = f2b(x0.x);
    p[(n_off+1)*40 + k_loc] = f2b(x0.y);
    p[(n_off+2)*40 + k_loc] = f2b(x0.z);
    p[(n_off+3)*40 + k_loc] = f2b(x0.w);
    p[(n_off+4)*40 + k_loc] = f2b(x1.x);
    p[(n_off+5)*40 + k_loc] = f2b(x1.y);
    p[(n_off+6)*40 + k_loc] = f2b(x1.z);
    p[(n_off+7)*40 + k_loc] = f2b(x1.w);
  };
  LD(0); ST(0);
  for(int c=0; c<nc; ++c){
    if(c+1 < nc) LD(c+1);
    int kk = k0b + c*32 + akof;
    float4 s0 = *(const float4*)(b1 + kk);
    float4 s1 = *(const float4*)(b1 + kk + 4);
    #pragma unroll
    for(int p=0; p<8; ++p){
      const float* fp = fpart + ((size_t)p*16 + arow)*4096 + kk;
      float4 p0 = *(const float4*)fp;
      float4 p1 = *(const float4*)(fp + 4);
      s0.x+=p0.x; s0.y+=p0.y; s0.z+=p0.z; s0.w+=p0.w;
      s1.x+=p1.x; s1.y+=p1.y; s1.z+=p1.z; s1.w+=p1.w;
    }
    bf16x8 af;
    af[0]=(short)f2b(fmaxf(s0.x,0.f)); af[1]=(short)f2b(fmaxf(s0.y,0.f));
    af[2]=(short)f2b(fmaxf(s0.z,0.f)); af[3]=(short)f2b(fmaxf(s0.w,0.f));
    af[4]=(short)f2b(fmaxf(s1.x,0.f)); af[5]=(short)f2b(fmaxf(s1.y,0.f));
    af[6]=(short)f2b(fmaxf(s1.z,0.f)); af[7]=(short)f2b(fmaxf(s1.w,0.f));
    __syncthreads();
    bf16x8 bv = *(const bf16x8*)&lt[c&1][(w*16 + (lane & 15))*40 + (lane >> 4)*8];
    acc = mfma16(af, bv, acc);
    if(c+1 < nc) ST((c+1)&1);
  }
  int col = n0 + w*16 + (lane & 15);
  int r0 = (lane >> 4)*4;
  #pragma unroll
  for(int i=0;i<4;++i)
    part[ ((size_t)ks*16 + r0 + i)*(size_t)N + col ] = acc[i];
}

// ---------------------------------------------------------------------------
extern "C" void kernel_launch(void* const* d_in, const int* in_sizes, int n_in,
                              void* d_out, int out_size, void* d_ws, size_t ws_size,
                              hipStream_t stream){
  const float* dec    = (const float*)d_in[0];
  const float* hist   = (const float*)d_in[1];
  const float* enc    = (const float*)d_in[2];
  const float* wq_s   = (const float*)d_in[3];
  const float* wk_s   = (const float*)d_in[4];
  const float* wv_s   = (const float*)d_in[5];
  const float* wo_s   = (const float*)d_in[6];
  const float* bo_s   = (const float*)d_in[7];
  const float* ln1_g  = (const float*)d_in[8];
  const float* ln1_b  = (const float*)d_in[9];
  const float* wq_c   = (const float*)d_in[10];
  const float* wk_c   = (const float*)d_in[11];
  const float* wv_c   = (const float*)d_in[12];
  const float* wo_c   = (const float*)d_in[13];
  const float* bo_c   = (const float*)d_in[14];
  const float* ln2_g  = (const float*)d_in[15];
  const float* ln2_b  = (const float*)d_in[16];
  const float* w1     = (const float*)d_in[17];
  const float* b1     = (const float*)d_in[18];
  const float* w2     = (const float*)d_in[19];
  const float* b2     = (const float*)d_in[20];
  const float* ln3_g  = (const float*)d_in[21];
  const float* ln3_b  = (const float*)d_in[22];

  float* out  = (float*)d_out;
  float* slf  = out + 16384;
  float* enco = out + 16384 + 524288;

  char* w = (char*)d_ws;
  float*          scr    = (float*)(w + 0x0000000);
  unsigned short* partb  = (unsigned short*)(w + 0x0200000);
  float*          msum   = (float*)(w + 0x2200000);
  unsigned short* qpb    = (unsigned short*)(w + 0x2240000);
  unsigned short* ctxb   = (unsigned short*)(w + 0x22C0000);
  float*          Qpart  = (float*)(w + 0x2340000);
  float*          opart  = (float*)(w + 0x23C0000);
  float*          x1     = (float*)(w + 0x2450000);
  float*          x2     = (float*)(w + 0x2460000);
  unsigned short* x2b    = (unsigned short*)(w + 0x2470000);
  float*          gpart  = (float*)(w + 0x2500000);
  float*          fpart  = (float*)(w + 0x2600000);
  float*          g2part = (float*)(w + 0x2800000);

  // ---- self attention ----
  g_qA   <<<dim3(8,16),  256, 0, stream>>>(dec, wq_s, Qpart);
  g_qB   <<<dim3(16,16), 256, 0, stream>>>(wk_s, Qpart, qpb);
  g_attn <<<512,  256, 0, stream>>>(hist, dec, qpb, scr, partb, msum, 2047, 4);
  g_comb <<<dim3(4,256), 256, 0, stream>>>(msum, scr, partb, slf, ctxb);
  g_vproj<<<dim3(8,16),  256, 0, stream>>>(wv_s, ctxb, opart);
  g_skgo <<<dim3(16,16), 256, 0, stream>>>(wo_s, opart, gpart);
  g_ln   <<<16,   256, 0, stream>>>(gpart, 16, bo_s, dec, ln1_g, ln1_b, x1, (unsigned short*)0, 100);

  // ---- cross attention ----
  g_qA   <<<dim3(8,16),  256, 0, stream>>>(x1, wq_c, Qpart);
  g_qB   <<<dim3(16,16), 256, 0, stream>>>(wk_c, Qpart, qpb);
  g_attn <<<512,  256, 0, stream>>>(enc, dec, qpb, scr, partb, msum, 2048, 4);
  g_comb <<<dim3(4,256), 256, 0, stream>>>(msum, scr, partb, enco, ctxb);
  g_vproj<<<dim3(8,16),  256, 0, stream>>>(wv_c, ctxb, opart);
  g_skgo <<<dim3(16,16), 256, 0, stream>>>(wo_c, opart, gpart);
  g_ln   <<<16,   256, 0, stream>>>(gpart, 16, bo_c, x1, ln2_g, ln2_b, x2, x2b, 100);

  // ---- FFN + final LN ----
  g_skg  <<<dim3(64,8),  256, 0, stream>>>(w1, x2b, fpart, 4096, 1024, 8);
  g_skgf <<<dim3(16,32), 256, 0, stream>>>(w2, fpart, b1, g2part);
  g_ln   <<<16,  256, 0, stream>>>(g2part, 32, b2, x2, ln3_g, ln3_b, out, (unsigned short*)0, 100);
}

// Round 16
// 198.690 us; speedup vs baseline: 5.0104x; 5.0104x over previous
//
#include <hip/hip_runtime.h>
#include <hip/hip_bf16.h>
#include <stdint.h>
#include <stddef.h>

// DecoderStepLayer R16: R14 base (167.5us) + comb/vproj fused into g_cv
// (grid (8,16)=128 blocks, keeps the MFMA V-proj shape; removes ctxb
// round-trip and 2 launches -> 15 total). Measured units: attn 22us (=BW
// roofline), ln 2.8us, boundary ~3.3-4us/launch.

#define DEV __device__ __forceinline__

typedef __attribute__((ext_vector_type(8))) short bf16x8;
typedef __attribute__((ext_vector_type(4))) short bf16x4;
typedef __attribute__((ext_vector_type(4))) float f32x4;

DEV unsigned short f2b(float f){
  union { __hip_bfloat16 h; unsigned short u; } cv;
  cv.h = __float2bfloat16(f);
  return cv.u;
}
DEV float b2f(unsigned short u){
  union { unsigned int i; float f; } cv;
  cv.i = ((unsigned int)u) << 16;
  return cv.f;
}
DEV f32x4 mfma16(bf16x8 a, bf16x8 b, f32x4 c){
  return __builtin_amdgcn_mfma_f32_16x16x32_bf16(a, b, c, 0, 0, 0);
}

// ---------------------------------------------------------------------------
// qA: Qpart[h][ks][b][k] = sum_{d' in 128-slice} src[b,d']*wq[h,d',k]
__global__ __launch_bounds__(256) void g_qA(const float* __restrict__ src,
    const float* __restrict__ wq, float* __restrict__ Qpart){
  int ks = blockIdx.x, h = blockIdx.y;
  int k0b = ks*128;
  __shared__ unsigned short lt[2][64*40];
  int t = threadIdx.x, lane = t & 63, w = t >> 6;
  int k_loc = t >> 3, n_off = (t & 7)*8;
  const float* apf = src + (size_t)(lane & 15)*1024 + (lane >> 4)*8 + k0b;
  const float* Wb = wq + (size_t)h*65536;
  f32x4 acc = {0.f,0.f,0.f,0.f};
  float4 x0, x1;
  auto LD = [&](int c){
    const float* wp = Wb + (size_t)(k0b + c*32 + k_loc)*64 + n_off;
    x0 = *(const float4*)wp;
    x1 = *(const float4*)(wp + 4);
  };
  auto ST = [&](int buf){
    unsigned short* p = &lt[buf][0];
    p[(n_off+0)*40 + k_loc] = f2b(x0.x);
    p[(n_off+1)*40 + k_loc] = f2b(x0.y);
    p[(n_off+2)*40 + k_loc] = f2b(x0.z);
    p[(n_off+3)*40 + k_loc] = f2b(x0.w);
    p[(n_off+4)*40 + k_loc] = f2b(x1.x);
    p[(n_off+5)*40 + k_loc] = f2b(x1.y);
    p[(n_off+6)*40 + k_loc] = f2b(x1.z);
    p[(n_off+7)*40 + k_loc] = f2b(x1.w);
  };
  LD(0); ST(0);
  for(int c=0; c<4; ++c){
    if(c+1 < 4) LD(c+1);
    __syncthreads();
    float4 a0 = *(const float4*)(apf + c*32);
    float4 a1 = *(const float4*)(apf + c*32 + 4);
    bf16x8 af;
    af[0]=(short)f2b(a0.x); af[1]=(short)f2b(a0.y);
    af[2]=(short)f2b(a0.z); af[3]=(short)f2b(a0.w);
    af[4]=(short)f2b(a1.x); af[5]=(short)f2b(a1.y);
    af[6]=(short)f2b(a1.z); af[7]=(short)f2b(a1.w);
    bf16x8 bv = *(const bf16x8*)&lt[c&1][(w*16 + (lane & 15))*40 + (lane >> 4)*8];
    acc = mfma16(af, bv, acc);
    if(c+1 < 4) ST((c+1)&1);
  }
  int col = w*16 + (lane & 15);
  int r0 = (lane >> 4)*4;
  #pragma unroll
  for(int i=0;i<4;++i)
    Qpart[ ((size_t)(h*8 + ks)*16 + r0 + i)*64 + col ] = acc[i];
}

// ---------------------------------------------------------------------------
// qB: qpb[b][h][d] = bf16( sum_k wk[h,d,k] * 0.125*sum_ks Qpart[h][ks][b][k] )
__global__ __launch_bounds__(256) void g_qB(const float* __restrict__ wk,
    const float* __restrict__ Qpart, unsigned short* __restrict__ qpb){
  int dt = blockIdx.x, h = blockIdx.y;
  int t = threadIdx.x;
  __shared__ float Qs[1024];
  #pragma unroll
  for(int i=0;i<4;++i){
    int idx = i*256 + t;
    float s = 0.f;
    #pragma unroll
    for(int ks=0; ks<8; ++ks)
      s += Qpart[((size_t)h<<13) + (ks<<10) + idx];
    Qs[idx] = s * 0.125f;
  }
  __syncthreads();
  int d_loc = t & 63, bg = t >> 6;
  const float* wr = wk + (size_t)h*65536 + (size_t)(dt*64 + d_loc)*64;
  float acc[4] = {0.f,0.f,0.f,0.f};
  #pragma unroll
  for(int k4=0; k4<16; ++k4){
    float4 w4 = *(const float4*)(wr + k4*4);
    #pragma unroll
    for(int i=0;i<4;++i){
      const float* q = &Qs[(bg*4+i)*64 + k4*4];
      acc[i] += w4.x*q[0] + w4.y*q[1] + w4.z*q[2] + w4.w*q[3];
    }
  }
  #pragma unroll
  for(int i=0;i<4;++i)
    qpb[ ((size_t)(bg*4+i)*16 + h)*1024 + dt*64 + d_loc ] = f2b(acc[i]);
}

// ---------------------------------------------------------------------------
// attn: grid 512 = (ns 32, b 16). Block = 64 rows, 4 chunks of 16. (22us = BW)
__global__ __launch_bounds__(256) void g_attn(const float* __restrict__ kvsrc,
    const float* __restrict__ decrow, const unsigned short* __restrict__ qpb,
    float* __restrict__ scr, unsigned short* __restrict__ partb,
    float* __restrict__ msum, int lsrc){
  int u = blockIdx.x, ns = u & 31, b = u >> 5;
  int t = threadIdx.x, lane = t & 63, w = t >> 6;
  int r = lane & 15, hi = lane >> 4;
  int slice0 = ns*64;

  __shared__ unsigned short lt[1024*20];
  __shared__ float red[1024];
  __shared__ unsigned short p_lds[16*40];
  __shared__ float f_lds[16];

  float4 ld[16];
  auto ISSUE = [&](int c){
    int row = slice0 + c*16 + r;
    const float* rpp = (row < lsrc) ? kvsrc + ((size_t)b*lsrc + row)*1024
                                    : decrow + (size_t)b*1024;
    rpp += w*256 + hi*8;
    #pragma unroll
    for(int kk=0; kk<8; ++kk){
      ld[kk*2+0] = *(const float4*)(rpp + kk*32);
      ld[kk*2+1] = *(const float4*)(rpp + kk*32 + 4);
    }
  };

  ISSUE(0);
  for(int i=t; i<16*40; i+=256) p_lds[i] = 0;

  bf16x8 qf[8];
  {
    const unsigned short* qp = qpb + ((size_t)b*16 + r)*1024 + w*256 + hi*8;
    #pragma unroll
    for(int kk=0;kk<8;++kk) qf[kk] = *(const bf16x8*)(qp + kk*32);
  }

  f32x4 acc[16];
  #pragma unroll
  for(int i=0;i<16;++i) acc[i] = (f32x4){0.f,0.f,0.f,0.f};
  float m_run = -1e30f, s_run = 0.f;

  __syncthreads();
  for(int c=0; c<4; ++c){
    f32x4 s_acc = {0.f,0.f,0.f,0.f};
    int colw = r ^ ((hi & 1) << 3);
    #pragma unroll
    for(int kk=0; kk<8; ++kk){
      float4 a0 = ld[kk*2], a1 = ld[kk*2+1];
      bf16x8 v;
      v[0]=(short)f2b(a0.x); v[1]=(short)f2b(a0.y);
      v[2]=(short)f2b(a0.z); v[3]=(short)f2b(a0.w);
      v[4]=(short)f2b(a1.x); v[5]=(short)f2b(a1.y);
      v[6]=(short)f2b(a1.z); v[7]=(short)f2b(a1.w);
      unsigned short* pt = &lt[(w*256 + hi*8 + kk*32)*20 + colw];
      #pragma unroll
      for(int j=0;j<8;++j) pt[j*20] = (unsigned short)v[j];
      s_acc = mfma16(v, qf[kk], s_acc);
    }
    if(c < 3) ISSUE(c+1);
    *(f32x4*)&red[t*4] = s_acc;
    __syncthreads();                       // (A)

    f32x4 ss = *(const f32x4*)&red[(0*64+lane)*4];
    ss += *(const f32x4*)&red[(1*64+lane)*4];
    ss += *(const f32x4*)&red[(2*64+lane)*4];
    ss += *(const f32x4*)&red[(3*64+lane)*4];
    float sf[4] = {ss[0], ss[1], ss[2], ss[3]};
    float mc = fmaxf(fmaxf(sf[0],sf[1]), fmaxf(sf[2],sf[3]));
    mc = fmaxf(mc, __shfl_xor(mc, 16));
    mc = fmaxf(mc, __shfl_xor(mc, 32));
    float nm = fmaxf(m_run, mc);
    float fch = __expf(m_run - nm);
    float pvv[4]; float ps = 0.f;
    #pragma unroll
    for(int i=0;i<4;++i){ pvv[i] = __expf(sf[i]-nm); ps += pvv[i]; }
    ps += __shfl_xor(ps, 16);
    ps += __shfl_xor(ps, 32);
    s_run = s_run*fch + ps;
    m_run = nm;
    if(w == 0){
      #pragma unroll
      for(int i=0;i<4;++i) p_lds[r*40 + hi*4 + i] = f2b(pvv[i]);
      if(hi == 0) f_lds[r] = fch;
      float* sp = scr + ((size_t)b*16 + r)*2048 + slice0 + c*16 + hi*4;
      *(float4*)sp = (float4){sf[0], sf[1], sf[2], sf[3]};
    }
    __syncthreads();                       // (B)

    f32x4 fv = *(const f32x4*)&f_lds[hi*4];
    bf16x8 pa = *(const bf16x8*)&p_lds[r*40 + hi*8];
    #pragma unroll
    for(int dc=0; dc<16; ++dc){
      acc[dc] *= fv;
      int d = w*256 + dc*16 + r;
      int col0 = (((hi & 1) ^ ((r >> 3) & 1)) << 3);
      bf16x4 blo = *(const bf16x4*)&lt[d*20 + col0];
      bf16x4 bhi = *(const bf16x4*)&lt[d*20 + col0 + 4];
      bf16x8 bv;
      bv[0]=blo[0]; bv[1]=blo[1]; bv[2]=blo[2]; bv[3]=blo[3];
      bv[4]=bhi[0]; bv[5]=bhi[1]; bv[6]=bhi[2]; bv[7]=bhi[3];
      acc[dc] = mfma16(pa, bv, acc[dc]);
    }
    __syncthreads();                       // (C)
  }
  unsigned short* pl = lt;
  #pragma unroll
  for(int dc=0; dc<16; ++dc)
    #pragma unroll
    for(int i=0;i<4;++i)
      pl[(hi*4+i)*1024 + w*256 + dc*16 + r] = f2b(acc[dc][i]);
  __syncthreads();
  {
    const uint4* s4 = (const uint4*)pl;
    uint4* d4 = (uint4*)(partb + (((size_t)b*32 + ns)*16)*1024);
    #pragma unroll
    for(int j=0;j<8;++j) d4[t + j*256] = s4[t + j*256];
  }
  if(w==0 && hi==0){
    msum[(((size_t)b*32 + ns)*16 + r)*2 + 0] = m_run;
    msum[(((size_t)b*32 + ns)*16 + r)*2 + 1] = s_run;
  }
}

// ---------------------------------------------------------------------------
// cv: fused comb+vproj. grid (ks 8, h 16), blk 256.
//  1) slice-weights e[b][ns] from msum
//  2) probs l-slice [ks*256,+256) for all b
//  3) ctx d-slice [ks*128,+128) for all b -> bf16 LDS tile (pitch 136)
//  4) MFMA: opart[h][ks][b][v] = ctx_slice @ wv[h][kslice]
__global__ __launch_bounds__(256) void g_cv(const float* __restrict__ msum,
    const float* __restrict__ scr, const unsigned short* __restrict__ partb,
    const float* __restrict__ wv, float* __restrict__ attn_out,
    float* __restrict__ opart){
  int ks = blockIdx.x, h = blockIdx.y;
  int k0b = ks*128;
  __shared__ unsigned short lt[2][64*40];
  __shared__ unsigned short ctx_lds[16*136];
  __shared__ float m_a[512], s_a[512];
  __shared__ float e_lds[16][32];
  __shared__ float Mb[16], Ib[16];
  int t = threadIdx.x, lane = t & 63, w = t >> 6;
  int k_loc = t >> 3, n_off = (t & 7)*8;
  const float* Wb = wv + (size_t)h*65536;      // [1024 d][64 v]
  float4 x0, x1;
  auto LD = [&](int c){
    const float* wp = Wb + (size_t)(k0b + c*32 + k_loc)*64 + n_off;
    x0 = *(const float4*)wp;
    x1 = *(const float4*)(wp + 4);
  };
  auto ST = [&](int buf){
    unsigned short* p = &lt[buf][0];
    p[(n_off+0)*40 + k_loc] = f2b(x0.x);
    p[(n_off+1)*40 + k_loc] = f2b(x0.y);
    p[(n_off+2)*40 + k_loc] = f2b(x0.z);
    p[(n_off+3)*40 + k_loc] = f2b(x0.w);
    p[(n_off+4)*40 + k_loc] = f2b(x1.x);
    p[(n_off+5)*40 + k_loc] = f2b(x1.y);
    p[(n_off+6)*40 + k_loc] = f2b(x1.z);
    p[(n_off+7)*40 + k_loc] = f2b(x1.w);
  };
  LD(0); ST(0);                              // prefetch W tile 0 during phases 1-3
  // --- phase 1: load msum, per-b weights ---
  #pragma unroll
  for(int i=0;i<2;++i){
    int idx = t + i*256;                     // b = idx>>5, ns = idx&31
    int b = idx >> 5, ns = idx & 31;
    float2 ms = *(const float2*)&msum[(((size_t)b*32 + ns)*16 + h)*2];
    m_a[idx] = ms.x; s_a[idx] = ms.y;
  }
  __syncthreads();
  if(t < 16){
    int b = t;
    float M = -1e30f;
    for(int ns=0;ns<32;++ns) M = fmaxf(M, m_a[b*32+ns]);
    float S = 0.f;
    for(int ns=0;ns<32;++ns) S += __expf(m_a[b*32+ns]-M)*s_a[b*32+ns];
    float inv = 1.f/S;
    for(int ns=0;ns<32;++ns) e_lds[b][ns] = __expf(m_a[b*32+ns]-M)*inv;
    Mb[b] = M; Ib[b] = inv;
  }
  __syncthreads();
  // --- phase 2: probs l-slice ---
  {
    int l = ks*256 + t;
    #pragma unroll 4
    for(int b=0;b<16;++b){
      size_t off = ((size_t)b*16 + h)*2048 + l;
      attn_out[off] = __expf(scr[off]-Mb[b])*Ib[b];
    }
  }
  // --- phase 3: ctx d-slice -> ctx_lds bf16 [b 16][d 128 +pad8] ---
  {
    int d_loc = t & 127, bp = t >> 7;        // bp in {0,1}; 8 b's per thread
    int d = k0b + d_loc;
    float a[8];
    #pragma unroll
    for(int j=0;j<8;++j) a[j]=0.f;
    for(int ns=0; ns<32; ++ns){
      #pragma unroll
      for(int j=0;j<8;++j){
        int b = bp + j*2;
        a[j] += e_lds[b][ns]*b2f(partb[(((size_t)b*32+ns)*16 + h)*1024 + d]);
      }
    }
    #pragma unroll
    for(int j=0;j<8;++j) ctx_lds[(bp + j*2)*136 + d_loc] = f2b(a[j]);
  }
  // --- phase 4: MFMA o = ctx @ wv[h][kslice] ---
  f32x4 acc = {0.f,0.f,0.f,0.f};
  for(int c=0; c<4; ++c){
    if(c+1 < 4) LD(c+1);
    __syncthreads();                         // ctx_lds + lt[c] visible
    bf16x8 af = *(const bf16x8*)&ctx_lds[(lane & 15)*136 + (lane >> 4)*8 + c*32];
    bf16x8 bv = *(const bf16x8*)&lt[c&1][(w*16 + (lane & 15))*40 + (lane >> 4)*8];
    acc = mfma16(af, bv, acc);
    if(c+1 < 4) ST((c+1)&1);
  }
  int col = w*16 + (lane & 15);
  int r0 = (lane >> 4)*4;
  #pragma unroll
  for(int i=0;i<4;++i)
    opart[ ((size_t)(h*8 + ks)*16 + r0 + i)*64 + col ] = acc[i];
}

// ---------------------------------------------------------------------------
// skgo: wo-GEMM with ovred folded into the A-build. grid (nt 16, h 16).
__global__ __launch_bounds__(256) void g_skgo(const float* __restrict__ wo,
    const float* __restrict__ opart, float* __restrict__ gpart){
  const int N = 1024;
  int nt = blockIdx.x, h = blockIdx.y;
  int n0 = nt*64, k0b = h*64;
  __shared__ unsigned short lt[2][64*40];
  __shared__ float obs[1024];
  int t = threadIdx.x, lane = t & 63, w = t >> 6;
  int k_loc = t >> 3, n_off = (t & 7)*8;
  {
    const float* base = opart + (size_t)h*8*16*64;
    int o = t*4, b = o >> 6, v = o & 63;
    float4 s = {0.f,0.f,0.f,0.f};
    #pragma unroll
    for(int ksl=0; ksl<8; ++ksl){
      float4 p = *(const float4*)(base + (size_t)(ksl*16 + b)*64 + v);
      s.x+=p.x; s.y+=p.y; s.z+=p.z; s.w+=p.w;
    }
    *(float4*)&obs[o] = s;
  }
  f32x4 acc = {0.f,0.f,0.f,0.f};
  float4 x0, x1;
  auto LD = [&](int c){
    const float* wp = wo + (size_t)(k0b + c*32 + k_loc)*N + n0 + n_off;
    x0 = *(const float4*)wp;
    x1 = *(const float4*)(wp + 4);
  };
  auto ST = [&](int buf){
    unsigned short* p = &lt[buf][0];
    p[(n_off+0)*40 + k_loc] = f2b(x0.x);
    p[(n_off+1)*40 + k_loc] = f2b(x0.y);
    p[(n_off+2)*40 + k_loc] = f2b(x0.z);
    p[(n_off+3)*40 + k_loc] = f2b(x0.w);
    p[(n_off+4)*40 + k_loc] = f2b(x1.x);
    p[(n_off+5)*40 + k_loc] = f2b(x1.y);
    p[(n_off+6)*40 + k_loc] = f2b(x1.z);
    p[(n_off+7)*40 + k_loc] = f2b(x1.w);
  };
  LD(0); ST(0);
  int arow = lane & 15, akof = (lane >> 4)*8;
  for(int c=0; c<2; ++c){
    if(c+1 < 2) LD(c+1);
    __syncthreads();
    const float* ap = &obs[arow*64 + c*32 + akof];
    bf16x8 af;
    af[0]=(short)f2b(ap[0]); af[1]=(short)f2b(ap[1]);
    af[2]=(short)f2b(ap[2]); af[3]=(short)f2b(ap[3]);
    af[4]=(short)f2b(ap[4]); af[5]=(short)f2b(ap[5]);
    af[6]=(short)f2b(ap[6]); af[7]=(short)f2b(ap[7]);
    bf16x8 bv = *(const bf16x8*)&lt[c&1][(w*16 + (lane & 15))*40 + (lane >> 4)*8];
    acc = mfma16(af, bv, acc);
    if(c+1 < 2) ST((c+1)&1);
  }
  int col = n0 + w*16 + (lane & 15);
  int r0 = (lane >> 4)*4;
  #pragma unroll
  for(int i=0;i<4;++i)
    gpart[ ((size_t)h*16 + r0 + i)*(size_t)N + col ] = acc[i];
}

// ---------------------------------------------------------------------------
// LN( sum_ks parts + bias + resid ) * g + bb -> xout [+ bf16]. grid 16.
__global__ __launch_bounds__(256) void g_ln(const float* __restrict__ parts, int KS,
    const float* __restrict__ bias, const float* __restrict__ resid,
    const float* __restrict__ g, const float* __restrict__ bb,
    float* __restrict__ xout, unsigned short* __restrict__ xb16){
  int b = blockIdx.x, t = threadIdx.x;
  __shared__ float red[256];
  const float4* bias4  = (const float4*)bias;
  const float4* resid4 = (const float4*)resid + (size_t)b*256;
  const float4* parts4 = (const float4*)parts;
  float4 s = bias4[t];
  { float4 rr = resid4[t]; s.x+=rr.x; s.y+=rr.y; s.z+=rr.z; s.w+=rr.w; }
  #pragma unroll 4
  for(int k=0;k<KS;++k){
    float4 pp = parts4[((size_t)k*16 + b)*256 + t];
    s.x+=pp.x; s.y+=pp.y; s.z+=pp.z; s.w+=pp.w;
  }
  red[t] = s.x+s.y+s.z+s.w; __syncthreads();
  for(int off=128; off>0; off>>=1){ if(t<off) red[t]+=red[t+off]; __syncthreads(); }
  float mean = red[0]*(1.f/1024.f); __syncthreads();
  float dx=s.x-mean, dy=s.y-mean, dz=s.z-mean, dw=s.w-mean;
  red[t] = dx*dx+dy*dy+dz*dz+dw*dw; __syncthreads();
  for(int off=128; off>0; off>>=1){ if(t<off) red[t]+=red[t+off]; __syncthreads(); }
  float rstd = rsqrtf(red[0]*(1.f/1024.f) + 1e-5f);
  float4 g4 = ((const float4*)g)[t], b4 = ((const float4*)bb)[t];
  float4 y;
  y.x = dx*rstd*g4.x + b4.x;
  y.y = dy*rstd*g4.y + b4.y;
  y.z = dz*rstd*g4.z + b4.z;
  y.w = dw*rstd*g4.w + b4.w;
  if(xout) ((float4*)xout)[(size_t)b*256 + t] = y;
  if(xb16){
    ushort4 uu;
    uu.x = f2b(y.x); uu.y = f2b(y.y); uu.z = f2b(y.z); uu.w = f2b(y.w);
    ((ushort4*)xb16)[(size_t)b*256 + t] = uu;
  }
}

// ---------------------------------------------------------------------------
// skinny GEMM: part[ks,b,n] = A[16,Kslice] @ W[Kslice,N]   (A bf16)
__global__ __launch_bounds__(256) void g_skg(const float* __restrict__ W,
    const unsigned short* __restrict__ A, float* __restrict__ part,
    int N, int K, int KS){
  int nt = blockIdx.x, ks = blockIdx.y;
  int Ksl = K / KS, k0b = ks * Ksl, n0 = nt*64;
  int nc = Ksl >> 5;
  __shared__ unsigned short lt[2][64*40];
  int t = threadIdx.x, lane = t & 63, w = t >> 6;
  int k_loc = t >> 3, n_off = (t & 7)*8;
  const unsigned short* apb = A + (size_t)(lane & 15)*K + (lane >> 4)*8 + k0b;
  f32x4 acc = {0.f,0.f,0.f,0.f};
  float4 x0, x1;
  auto LD = [&](int c){
    const float* wp = W + (size_t)(k0b + c*32 + k_loc)*N + n0 + n_off;
    x0 = *(const float4*)wp;
    x1 = *(const float4*)(wp + 4);
  };
  auto ST = [&](int buf){
    unsigned short* p = &lt[buf][0];
    p[(n_off+0)*40 + k_loc] = f2b(x0.x);
    p[(n_off+1)*40 + k_loc] = f2b(x0.y);
    p[(n_off+2)*40 + k_loc] = f2b(x0.z);
    p[(n_off+3)*40 + k_loc] = f2b(x0.w);
    p[(n_off+4)*40 + k_loc] = f2b(x1.x);
    p[(n_off+5)*40 + k_loc] = f2b(x1.y);
    p[(n_off+6)*40 + k_loc] = f2b(x1.z);
    p[(n_off+7)*40 + k_loc] = f2b(x1.w);
  };
  LD(0); ST(0);
  for(int c=0; c<nc; ++c){
    if(c+1 < nc) LD(c+1);
    __syncthreads();
    bf16x8 af = *(const bf16x8*)(apb + c*32);
    bf16x8 bv = *(const bf16x8*)&lt[c&1][(w*16 + (lane & 15))*40 + (lane >> 4)*8];
    acc = mfma16(af, bv, acc);
    if(c+1 < nc) ST((c+1)&1);
  }
  int col = n0 + w*16 + (lane & 15);
  int r0 = (lane >> 4)*4;
  #pragma unroll
  for(int i=0;i<4;++i)
    part[ ((size_t)ks*16 + r0 + i)*(size_t)N + col ] = acc[i];
}

// ---------------------------------------------------------------------------
// skgf: FFN w2 GEMM with A = relu(sum_p fpart + b1) built in-register.
__global__ __launch_bounds__(256) void g_skgf(const float* __restrict__ W,
    const float* __restrict__ fpart, const float* __restrict__ b1,
    float* __restrict__ part){
  const int N = 1024, K = 4096, KS = 32;
  int nt = blockIdx.x, ks = blockIdx.y;
  int Ksl = K / KS, k0b = ks * Ksl, n0 = nt*64;
  int nc = Ksl >> 5;
  __shared__ unsigned short lt[2][64*40];
  int t = threadIdx.x, lane = t & 63, w = t >> 6;
  int k_loc = t >> 3, n_off = (t & 7)*8;
  int arow = lane & 15, akof = (lane >> 4)*8;
  f32x4 acc = {0.f,0.f,0.f,0.f};
  float4 x0, x1;
  auto LD = [&](int c){
    const float* wp = W + (size_t)(k0b + c*32 + k_loc)*N + n0 + n_off;
    x0 = *(const float4*)wp;
    x1 = *(const float4*)(wp + 4);
  };
  auto ST = [&](int buf){
    unsigned short* p = &lt[buf][0];
    p[(n_off+0)*40 + k_loc] = f2b(x0.x);
    p[(n_off+1)*40 + k_loc] = f2b(x0.y);
    p[(n_off+2)*40 + k_loc] = f2b(x0.z);
    p[(n_off+3)*40 + k_loc] = f2b(x0.w);
    p[(n_off+4)*40 + k_loc] = f2b(x1.x);
    p[(n_off+5)*40 + k_loc] = f2b(x1.y);
    p[(n_off+6)*40 + k_loc] = f2b(x1.z);
    p[(n_off+7)*40 + k_loc] = f2b(x1.w);
  };
  LD(0); ST(0);
  for(int c=0; c<nc; ++c){
    if(c+1 < nc) LD(c+1);
    int kk = k0b + c*32 + akof;
    float4 s0 = *(const float4*)(b1 + kk);
    float4 s1 = *(const float4*)(b1 + kk + 4);
    #pragma unroll
    for(int p=0; p<8; ++p){
      const float* fp = fpart + ((size_t)p*16 + arow)*4096 + kk;
      float4 p0 = *(const float4*)fp;
      float4 p1 = *(const float4*)(fp + 4);
      s0.x+=p0.x; s0.y+=p0.y; s0.z+=p0.z; s0.w+=p0.w;
      s1.x+=p1.x; s1.y+=p1.y; s1.z+=p1.z; s1.w+=p1.w;
    }
    bf16x8 af;
    af[0]=(short)f2b(fmaxf(s0.x,0.f)); af[1]=(short)f2b(fmaxf(s0.y,0.f));
    af[2]=(short)f2b(fmaxf(s0.z,0.f)); af[3]=(short)f2b(fmaxf(s0.w,0.f));
    af[4]=(short)f2b(fmaxf(s1.x,0.f)); af[5]=(short)f2b(fmaxf(s1.y,0.f));
    af[6]=(short)f2b(fmaxf(s1.z,0.f)); af[7]=(short)f2b(fmaxf(s1.w,0.f));
    __syncthreads();
    bf16x8 bv = *(const bf16x8*)&lt[c&1][(w*16 + (lane & 15))*40 + (lane >> 4)*8];
    acc = mfma16(af, bv, acc);
    if(c+1 < nc) ST((c+1)&1);
  }
  int col = n0 + w*16 + (lane & 15);
  int r0 = (lane >> 4)*4;
  #pragma unroll
  for(int i=0;i<4;++i)
    part[ ((size_t)ks*16 + r0 + i)*(size_t)N + col ] = acc[i];
}

// ---------------------------------------------------------------------------
extern "C" void kernel_launch(void* const* d_in, const int* in_sizes, int n_in,
                              void* d_out, int out_size, void* d_ws, size_t ws_size,
                              hipStream_t stream){
  const float* dec    = (const float*)d_in[0];
  const float* hist   = (const float*)d_in[1];
  const float* enc    = (const float*)d_in[2];
  const float* wq_s   = (const float*)d_in[3];
  const float* wk_s   = (const float*)d_in[4];
  const float* wv_s   = (const float*)d_in[5];
  const float* wo_s   = (const float*)d_in[6];
  const float* bo_s   = (const float*)d_in[7];
  const float* ln1_g  = (const float*)d_in[8];
  const float* ln1_b  = (const float*)d_in[9];
  const float* wq_c   = (const float*)d_in[10];
  const float* wk_c   = (const float*)d_in[11];
  const float* wv_c   = (const float*)d_in[12];
  const float* wo_c   = (const float*)d_in[13];
  const float* bo_c   = (const float*)d_in[14];
  const float* ln2_g  = (const float*)d_in[15];
  const float* ln2_b  = (const float*)d_in[16];
  const float* w1     = (const float*)d_in[17];
  const float* b1     = (const float*)d_in[18];
  const float* w2     = (const float*)d_in[19];
  const float* b2     = (const float*)d_in[20];
  const float* ln3_g  = (const float*)d_in[21];
  const float* ln3_b  = (const float*)d_in[22];

  float* out  = (float*)d_out;             // [16][1024]
  float* slf  = out + 16384;               // [16][16][2048]
  float* enco = out + 16384 + 524288;      // [16][16][2048]

  char* w = (char*)d_ws;
  float*          scr    = (float*)(w + 0x0000000);           // 2 MB
  unsigned short* partb  = (unsigned short*)(w + 0x0200000);  // 16 MB bf16
  float*          msum   = (float*)(w + 0x2200000);           // 64K
  unsigned short* qpb    = (unsigned short*)(w + 0x2240000);  // 512K
  float*          Qpart  = (float*)(w + 0x2340000);           // 512K
  float*          opart  = (float*)(w + 0x23C0000);           // 512K
  float*          x1     = (float*)(w + 0x2450000);           // 64K
  float*          x2     = (float*)(w + 0x2460000);           // 64K
  unsigned short* x2b    = (unsigned short*)(w + 0x2470000);  // 32K
  float*          gpart  = (float*)(w + 0x2500000);           // 1 MB
  float*          fpart  = (float*)(w + 0x2600000);           // 2 MB
  float*          g2part = (float*)(w + 0x2800000);           // 2 MB

  // ---- self attention ----
  g_qA   <<<dim3(8,16),  256, 0, stream>>>(dec, wq_s, Qpart);
  g_qB   <<<dim3(16,16), 256, 0, stream>>>(wk_s, Qpart, qpb);
  g_attn <<<512,  256, 0, stream>>>(hist, dec, qpb, scr, partb, msum, 2047);
  g_cv   <<<dim3(8,16),  256, 0, stream>>>(msum, scr, partb, wv_s, slf, opart);
  g_skgo <<<dim3(16,16), 256, 0, stream>>>(wo_s, opart, gpart);
  g_ln   <<<16,   256, 0, stream>>>(gpart, 16, bo_s, dec, ln1_g, ln1_b, x1, (unsigned short*)0);

  // ---- cross attention ----
  g_qA   <<<dim3(8,16),  256, 0, stream>>>(x1, wq_c, Qpart);
  g_qB   <<<dim3(16,16), 256, 0, stream>>>(wk_c, Qpart, qpb);
  g_attn <<<512,  256, 0, stream>>>(enc, dec, qpb, scr, partb, msum, 2048);
  g_cv   <<<dim3(8,16),  256, 0, stream>>>(msum, scr, partb, wv_c, enco, opart);
  g_skgo <<<dim3(16,16), 256, 0, stream>>>(wo_c, opart, gpart);
  g_ln   <<<16,   256, 0, stream>>>(gpart, 16, bo_c, x1, ln2_g, ln2_b, x2, x2b);

  // ---- FFN + final LN ----
  g_skg  <<<dim3(64,8),  256, 0, stream>>>(w1, x2b, fpart, 4096, 1024, 8);
  g_skgf <<<dim3(16,32), 256, 0, stream>>>(w2, fpart, b1, g2part);
  g_ln   <<<16,  256, 0, stream>>>(g2part, 32, b2, x2, ln3_g, ln3_b, out, (unsigned short*)0);
}

// Round 17
// 167.439 us; speedup vs baseline: 5.9456x; 1.1866x over previous
//
#include <hip/hip_runtime.h>
#include <hip/hip_bf16.h>
#include <stdint.h>
#include <stddef.h>

// DecoderStepLayer R17: restore of R14 (verified 167.5us; best = R12 166.8
// within noise). R16's g_cv fusion regressed (+31us: 16MB combine at 128
// blocks = low-parallelism disease) -> reverted to comb(1024 blk)+vproj(128).
// Structure: qA/qB (q-path MFMA split), attn (512 blk, BW roofline 22us x2),
// comb, vproj, skgo (wo+ovred), ln, FFN skg + skgf(relu-fused). 17 launches.
// Overhead model: ~65us serial-stage ramp/drain, resistant to fusion (R6/R13/
// R16 all failed); attn at HBM roofline; remaining kernels 2-7us each.

#define DEV __device__ __forceinline__

typedef __attribute__((ext_vector_type(8))) short bf16x8;
typedef __attribute__((ext_vector_type(4))) short bf16x4;
typedef __attribute__((ext_vector_type(4))) float f32x4;

DEV unsigned short f2b(float f){
  union { __hip_bfloat16 h; unsigned short u; } cv;
  cv.h = __float2bfloat16(f);
  return cv.u;
}
DEV float b2f(unsigned short u){
  union { unsigned int i; float f; } cv;
  cv.i = ((unsigned int)u) << 16;
  return cv.f;
}
DEV f32x4 mfma16(bf16x8 a, bf16x8 b, f32x4 c){
  return __builtin_amdgcn_mfma_f32_16x16x32_bf16(a, b, c, 0, 0, 0);
}

// ---------------------------------------------------------------------------
// qA: Qpart[h][ks][b][k] = sum_{d' in 128-slice} src[b,d']*wq[h,d',k]
__global__ __launch_bounds__(256) void g_qA(const float* __restrict__ src,
    const float* __restrict__ wq, float* __restrict__ Qpart){
  int ks = blockIdx.x, h = blockIdx.y;
  int k0b = ks*128;
  __shared__ unsigned short lt[2][64*40];
  int t = threadIdx.x, lane = t & 63, w = t >> 6;
  int k_loc = t >> 3, n_off = (t & 7)*8;
  const float* apf = src + (size_t)(lane & 15)*1024 + (lane >> 4)*8 + k0b;
  const float* Wb = wq + (size_t)h*65536;      // [1024 d'][64 k] row-major
  f32x4 acc = {0.f,0.f,0.f,0.f};
  float4 x0, x1;
  auto LD = [&](int c){
    const float* wp = Wb + (size_t)(k0b + c*32 + k_loc)*64 + n_off;
    x0 = *(const float4*)wp;
    x1 = *(const float4*)(wp + 4);
  };
  auto ST = [&](int buf){
    unsigned short* p = &lt[buf][0];
    p[(n_off+0)*40 + k_loc] = f2b(x0.x);
    p[(n_off+1)*40 + k_loc] = f2b(x0.y);
    p[(n_off+2)*40 + k_loc] = f2b(x0.z);
    p[(n_off+3)*40 + k_loc] = f2b(x0.w);
    p[(n_off+4)*40 + k_loc] = f2b(x1.x);
    p[(n_off+5)*40 + k_loc] = f2b(x1.y);
    p[(n_off+6)*40 + k_loc] = f2b(x1.z);
    p[(n_off+7)*40 + k_loc] = f2b(x1.w);
  };
  LD(0); ST(0);
  for(int c=0; c<4; ++c){
    if(c+1 < 4) LD(c+1);
    __syncthreads();
    float4 a0 = *(const float4*)(apf + c*32);
    float4 a1 = *(const float4*)(apf + c*32 + 4);
    bf16x8 af;
    af[0]=(short)f2b(a0.x); af[1]=(short)f2b(a0.y);
    af[2]=(short)f2b(a0.z); af[3]=(short)f2b(a0.w);
    af[4]=(short)f2b(a1.x); af[5]=(short)f2b(a1.y);
    af[6]=(short)f2b(a1.z); af[7]=(short)f2b(a1.w);
    bf16x8 bv = *(const bf16x8*)&lt[c&1][(w*16 + (lane & 15))*40 + (lane >> 4)*8];
    acc = mfma16(af, bv, acc);
    if(c+1 < 4) ST((c+1)&1);
  }
  int col = w*16 + (lane & 15);
  int r0 = (lane >> 4)*4;
  #pragma unroll
  for(int i=0;i<4;++i)
    Qpart[ ((size_t)(h*8 + ks)*16 + r0 + i)*64 + col ] = acc[i];
}

// ---------------------------------------------------------------------------
// qB: qpb[b][h][d] = bf16( sum_k wk[h,d,k] * 0.125*sum_ks Qpart[h][ks][b][k] )
__global__ __launch_bounds__(256) void g_qB(const float* __restrict__ wk,
    const float* __restrict__ Qpart, unsigned short* __restrict__ qpb){
  int dt = blockIdx.x, h = blockIdx.y;
  int t = threadIdx.x;
  __shared__ float Qs[1024];               // [b 16][k 64]
  #pragma unroll
  for(int i=0;i<4;++i){
    int idx = i*256 + t;                   // b = idx>>6, k = idx&63
    float s = 0.f;
    #pragma unroll
    for(int ks=0; ks<8; ++ks)
      s += Qpart[((size_t)h<<13) + (ks<<10) + idx];
    Qs[idx] = s * 0.125f;
  }
  __syncthreads();
  int d_loc = t & 63, bg = t >> 6;         // wave-uniform bg -> Qs broadcast
  const float* wr = wk + (size_t)h*65536 + (size_t)(dt*64 + d_loc)*64;
  float acc[4] = {0.f,0.f,0.f,0.f};
  #pragma unroll
  for(int k4=0; k4<16; ++k4){
    float4 w4 = *(const float4*)(wr + k4*4);
    #pragma unroll
    for(int i=0;i<4;++i){
      const float* q = &Qs[(bg*4+i)*64 + k4*4];
      acc[i] += w4.x*q[0] + w4.y*q[1] + w4.z*q[2] + w4.w*q[3];
    }
  }
  #pragma unroll
  for(int i=0;i<4;++i)
    qpb[ ((size_t)(bg*4+i)*16 + h)*1024 + dt*64 + d_loc ] = f2b(acc[i]);
}

// ---------------------------------------------------------------------------
// attn: grid 512 = (ns 32, b 16). Block = 64 rows, 4 chunks of 16. (22us = BW)
__global__ __launch_bounds__(256) void g_attn(const float* __restrict__ kvsrc,
    const float* __restrict__ decrow, const unsigned short* __restrict__ qpb,
    float* __restrict__ scr, unsigned short* __restrict__ partb,
    float* __restrict__ msum, int lsrc){
  int u = blockIdx.x, ns = u & 31, b = u >> 5;
  int t = threadIdx.x, lane = t & 63, w = t >> 6;
  int r = lane & 15, hi = lane >> 4;
  int slice0 = ns*64;

  __shared__ unsigned short lt[1024*20];
  __shared__ float red[1024];
  __shared__ unsigned short p_lds[16*40];
  __shared__ float f_lds[16];

  float4 ld[16];
  auto ISSUE = [&](int c){
    int row = slice0 + c*16 + r;
    const float* rpp = (row < lsrc) ? kvsrc + ((size_t)b*lsrc + row)*1024
                                    : decrow + (size_t)b*1024;
    rpp += w*256 + hi*8;
    #pragma unroll
    for(int kk=0; kk<8; ++kk){
      ld[kk*2+0] = *(const float4*)(rpp + kk*32);
      ld[kk*2+1] = *(const float4*)(rpp + kk*32 + 4);
    }
  };

  ISSUE(0);
  for(int i=t; i<16*40; i+=256) p_lds[i] = 0;

  bf16x8 qf[8];
  {
    const unsigned short* qp = qpb + ((size_t)b*16 + r)*1024 + w*256 + hi*8;
    #pragma unroll
    for(int kk=0;kk<8;++kk) qf[kk] = *(const bf16x8*)(qp + kk*32);
  }

  f32x4 acc[16];
  #pragma unroll
  for(int i=0;i<16;++i) acc[i] = (f32x4){0.f,0.f,0.f,0.f};
  float m_run = -1e30f, s_run = 0.f;

  __syncthreads();
  for(int c=0; c<4; ++c){
    f32x4 s_acc = {0.f,0.f,0.f,0.f};
    int colw = r ^ ((hi & 1) << 3);
    #pragma unroll
    for(int kk=0; kk<8; ++kk){
      float4 a0 = ld[kk*2], a1 = ld[kk*2+1];
      bf16x8 v;
      v[0]=(short)f2b(a0.x); v[1]=(short)f2b(a0.y);
      v[2]=(short)f2b(a0.z); v[3]=(short)f2b(a0.w);
      v[4]=(short)f2b(a1.x); v[5]=(short)f2b(a1.y);
      v[6]=(short)f2b(a1.z); v[7]=(short)f2b(a1.w);
      unsigned short* pt = &lt[(w*256 + hi*8 + kk*32)*20 + colw];
      #pragma unroll
      for(int j=0;j<8;++j) pt[j*20] = (unsigned short)v[j];
      s_acc = mfma16(v, qf[kk], s_acc);
    }
    if(c < 3) ISSUE(c+1);
    *(f32x4*)&red[t*4] = s_acc;
    __syncthreads();                       // (A) red + lt visible

    f32x4 ss = *(const f32x4*)&red[(0*64+lane)*4];
    ss += *(const f32x4*)&red[(1*64+lane)*4];
    ss += *(const f32x4*)&red[(2*64+lane)*4];
    ss += *(const f32x4*)&red[(3*64+lane)*4];
    float sf[4] = {ss[0], ss[1], ss[2], ss[3]};
    float mc = fmaxf(fmaxf(sf[0],sf[1]), fmaxf(sf[2],sf[3]));
    mc = fmaxf(mc, __shfl_xor(mc, 16));
    mc = fmaxf(mc, __shfl_xor(mc, 32));
    float nm = fmaxf(m_run, mc);
    float fch = __expf(m_run - nm);
    float pvv[4]; float ps = 0.f;
    #pragma unroll
    for(int i=0;i<4;++i){ pvv[i] = __expf(sf[i]-nm); ps += pvv[i]; }
    ps += __shfl_xor(ps, 16);
    ps += __shfl_xor(ps, 32);
    s_run = s_run*fch + ps;
    m_run = nm;
    if(w == 0){
      #pragma unroll
      for(int i=0;i<4;++i) p_lds[r*40 + hi*4 + i] = f2b(pvv[i]);
      if(hi == 0) f_lds[r] = fch;
      float* sp = scr + ((size_t)b*16 + r)*2048 + slice0 + c*16 + hi*4;
      *(float4*)sp = (float4){sf[0], sf[1], sf[2], sf[3]};
    }
    __syncthreads();                       // (B) p_lds, f_lds ready

    f32x4 fv = *(const f32x4*)&f_lds[hi*4];
    bf16x8 pa = *(const bf16x8*)&p_lds[r*40 + hi*8];
    #pragma unroll
    for(int dc=0; dc<16; ++dc){
      acc[dc] *= fv;
      int d = w*256 + dc*16 + r;
      int col0 = (((hi & 1) ^ ((r >> 3) & 1)) << 3);
      bf16x4 blo = *(const bf16x4*)&lt[d*20 + col0];
      bf16x4 bhi = *(const bf16x4*)&lt[d*20 + col0 + 4];
      bf16x8 bv;
      bv[0]=blo[0]; bv[1]=blo[1]; bv[2]=blo[2]; bv[3]=blo[3];
      bv[4]=bhi[0]; bv[5]=bhi[1]; bv[6]=bhi[2]; bv[7]=bhi[3];
      acc[dc] = mfma16(pa, bv, acc[dc]);
    }
    __syncthreads();                       // (C)
  }
  unsigned short* pl = lt;                 // reuse: [h 16][d 1024]
  #pragma unroll
  for(int dc=0; dc<16; ++dc)
    #pragma unroll
    for(int i=0;i<4;++i)
      pl[(hi*4+i)*1024 + w*256 + dc*16 + r] = f2b(acc[dc][i]);
  __syncthreads();
  {
    const uint4* s4 = (const uint4*)pl;
    uint4* d4 = (uint4*)(partb + (((size_t)b*32 + ns)*16)*1024);
    #pragma unroll
    for(int j=0;j<8;++j) d4[t + j*256] = s4[t + j*256];
  }
  if(w==0 && hi==0){
    msum[(((size_t)b*32 + ns)*16 + r)*2 + 0] = m_run;
    msum[(((size_t)b*32 + ns)*16 + r)*2 + 1] = s_run;
  }
}

// ---------------------------------------------------------------------------
// comb: grid (dq 4, bh 256), blk 256. 32-slice combine + probs + bf16 ctx.
__global__ __launch_bounds__(256) void g_comb(const float* __restrict__ msum,
    const float* __restrict__ scr, const unsigned short* __restrict__ partb,
    float* __restrict__ attn_out, unsigned short* __restrict__ ctxb){
  int dq = blockIdx.x, bh = blockIdx.y, b = bh >> 4, h = bh & 15;
  int t = threadIdx.x;
  __shared__ float e_lds[32];
  __shared__ float Mi[2];
  if(t < 32){
    float2 ms = *(const float2*)&msum[(((size_t)b*32 + t)*16 + h)*2];
    float M = ms.x;
    #pragma unroll
    for(int o=1; o<32; o<<=1) M = fmaxf(M, __shfl_xor(M, o));
    float e = __expf(ms.x - M)*ms.y;
    float S = e;
    #pragma unroll
    for(int o=1; o<32; o<<=1) S += __shfl_xor(S, o);
    e_lds[t] = __expf(ms.x - M)/S;
    if(t == 0){ Mi[0] = M; Mi[1] = 1.f/S; }
  }
  __syncthreads();
  float M = Mi[0], inv = Mi[1];
  const float* sp = scr + (size_t)bh*2048 + dq*512;
  float* po = attn_out + (size_t)bh*2048 + dq*512;
  po[t]     = __expf(sp[t]     - M)*inv;
  po[t+256] = __expf(sp[t+256] - M)*inv;
  int d = dq*256 + t;
  const unsigned short* pb0 = partb + ((size_t)b*32*16 + h)*1024 + d;
  float acc = 0.f;
  #pragma unroll 8
  for(int ns=0; ns<32; ++ns)
    acc += e_lds[ns]*b2f(pb0[(size_t)ns*16384]);
  ctxb[(size_t)bh*1024 + d] = f2b(acc);
}

// ---------------------------------------------------------------------------
// vproj: opart[h][ks][b][v] = sum_{d in 128-slice} ctxb[b][h][d]*wv[h][d][v]
__global__ __launch_bounds__(256) void g_vproj(const float* __restrict__ wv,
    const unsigned short* __restrict__ ctxb, float* __restrict__ opart){
  int ks = blockIdx.x, h = blockIdx.y;
  int k0b = ks*128;
  __shared__ unsigned short lt[2][64*40];
  int t = threadIdx.x, lane = t & 63, w = t >> 6;
  int k_loc = t >> 3, n_off = (t & 7)*8;
  const unsigned short* apb = ctxb + (size_t)(lane & 15)*16384 + (size_t)h*1024
                              + (lane >> 4)*8 + k0b;
  const float* Wb = wv + (size_t)h*65536;      // [1024 d][64 v]
  f32x4 acc = {0.f,0.f,0.f,0.f};
  float4 x0, x1;
  auto LD = [&](int c){
    const float* wp = Wb + (size_t)(k0b + c*32 + k_loc)*64 + n_off;
    x0 = *(const float4*)wp;
    x1 = *(const float4*)(wp + 4);
  };
  auto ST = [&](int buf){
    unsigned short* p = &lt[buf][0];
    p[(n_off+0)*40 + k_loc] = f2b(x0.x);
    p[(n_off+1)*40 + k_loc] = f2b(x0.y);
    p[(n_off+2)*40 + k_loc] = f2b(x0.z);
    p[(n_off+3)*40 + k_loc] = f2b(x0.w);
    p[(n_off+4)*40 + k_loc] = f2b(x1.x);
    p[(n_off+5)*40 + k_loc] = f2b(x1.y);
    p[(n_off+6)*40 + k_loc] = f2b(x1.z);
    p[(n_off+7)*40 + k_loc] = f2b(x1.w);
  };
  LD(0); ST(0);
  for(int c=0; c<4; ++c){
    if(c+1 < 4) LD(c+1);
    __syncthreads();
    bf16x8 af = *(const bf16x8*)(apb + c*32);
    bf16x8 bv = *(const bf16x8*)&lt[c&1][(w*16 + (lane & 15))*40 + (lane >> 4)*8];
    acc = mfma16(af, bv, acc);
    if(c+1 < 4) ST((c+1)&1);
  }
  int col = w*16 + (lane & 15);
  int r0 = (lane >> 4)*4;
  #pragma unroll
  for(int i=0;i<4;++i)
    opart[ ((size_t)(h*8 + ks)*16 + r0 + i)*64 + col ] = acc[i];
}

// ---------------------------------------------------------------------------
// skgo: wo-GEMM with ovred folded into the A-build. grid (nt 16, h 16).
__global__ __launch_bounds__(256) void g_skgo(const float* __restrict__ wo,
    const float* __restrict__ opart, float* __restrict__ gpart){
  const int N = 1024;
  int nt = blockIdx.x, h = blockIdx.y;
  int n0 = nt*64, k0b = h*64;
  __shared__ unsigned short lt[2][64*40];
  __shared__ float obs[1024];
  int t = threadIdx.x, lane = t & 63, w = t >> 6;
  int k_loc = t >> 3, n_off = (t & 7)*8;
  {
    const float* base = opart + (size_t)h*8*16*64;
    int o = t*4, b = o >> 6, v = o & 63;
    float4 s = {0.f,0.f,0.f,0.f};
    #pragma unroll
    for(int ksl=0; ksl<8; ++ksl){
      float4 p = *(const float4*)(base + (size_t)(ksl*16 + b)*64 + v);
      s.x+=p.x; s.y+=p.y; s.z+=p.z; s.w+=p.w;
    }
    *(float4*)&obs[o] = s;
  }
  f32x4 acc = {0.f,0.f,0.f,0.f};
  float4 x0, x1;
  auto LD = [&](int c){
    const float* wp = wo + (size_t)(k0b + c*32 + k_loc)*N + n0 + n_off;
    x0 = *(const float4*)wp;
    x1 = *(const float4*)(wp + 4);
  };
  auto ST = [&](int buf){
    unsigned short* p = &lt[buf][0];
    p[(n_off+0)*40 + k_loc] = f2b(x0.x);
    p[(n_off+1)*40 + k_loc] = f2b(x0.y);
    p[(n_off+2)*40 + k_loc] = f2b(x0.z);
    p[(n_off+3)*40 + k_loc] = f2b(x0.w);
    p[(n_off+4)*40 + k_loc] = f2b(x1.x);
    p[(n_off+5)*40 + k_loc] = f2b(x1.y);
    p[(n_off+6)*40 + k_loc] = f2b(x1.z);
    p[(n_off+7)*40 + k_loc] = f2b(x1.w);
  };
  LD(0); ST(0);
  int arow = lane & 15, akof = (lane >> 4)*8;
  for(int c=0; c<2; ++c){
    if(c+1 < 2) LD(c+1);
    __syncthreads();
    const float* ap = &obs[arow*64 + c*32 + akof];
    bf16x8 af;
    af[0]=(short)f2b(ap[0]); af[1]=(short)f2b(ap[1]);
    af[2]=(short)f2b(ap[2]); af[3]=(short)f2b(ap[3]);
    af[4]=(short)f2b(ap[4]); af[5]=(short)f2b(ap[5]);
    af[6]=(short)f2b(ap[6]); af[7]=(short)f2b(ap[7]);
    bf16x8 bv = *(const bf16x8*)&lt[c&1][(w*16 + (lane & 15))*40 + (lane >> 4)*8];
    acc = mfma16(af, bv, acc);
    if(c+1 < 2) ST((c+1)&1);
  }
  int col = n0 + w*16 + (lane & 15);
  int r0 = (lane >> 4)*4;
  #pragma unroll
  for(int i=0;i<4;++i)
    gpart[ ((size_t)h*16 + r0 + i)*(size_t)N + col ] = acc[i];
}

// ---------------------------------------------------------------------------
// LN( sum_ks parts + bias + resid ) * g + bb -> xout [+ bf16]. grid 16.
__global__ __launch_bounds__(256) void g_ln(const float* __restrict__ parts, int KS,
    const float* __restrict__ bias, const float* __restrict__ resid,
    const float* __restrict__ g, const float* __restrict__ bb,
    float* __restrict__ xout, unsigned short* __restrict__ xb16){
  int b = blockIdx.x, t = threadIdx.x;
  __shared__ float red[256];
  const float4* bias4  = (const float4*)bias;
  const float4* resid4 = (const float4*)resid + (size_t)b*256;
  const float4* parts4 = (const float4*)parts;
  float4 s = bias4[t];
  { float4 rr = resid4[t]; s.x+=rr.x; s.y+=rr.y; s.z+=rr.z; s.w+=rr.w; }
  #pragma unroll 4
  for(int k=0;k<KS;++k){
    float4 pp = parts4[((size_t)k*16 + b)*256 + t];
    s.x+=pp.x; s.y+=pp.y; s.z+=pp.z; s.w+=pp.w;
  }
  red[t] = s.x+s.y+s.z+s.w; __syncthreads();
  for(int off=128; off>0; off>>=1){ if(t<off) red[t]+=red[t+off]; __syncthreads(); }
  float mean = red[0]*(1.f/1024.f); __syncthreads();
  float dx=s.x-mean, dy=s.y-mean, dz=s.z-mean, dw=s.w-mean;
  red[t] = dx*dx+dy*dy+dz*dz+dw*dw; __syncthreads();
  for(int off=128; off>0; off>>=1){ if(t<off) red[t]+=red[t+off]; __syncthreads(); }
  float rstd = rsqrtf(red[0]*(1.f/1024.f) + 1e-5f);
  float4 g4 = ((const float4*)g)[t], b4 = ((const float4*)bb)[t];
  float4 y;
  y.x = dx*rstd*g4.x + b4.x;
  y.y = dy*rstd*g4.y + b4.y;
  y.z = dz*rstd*g4.z + b4.z;
  y.w = dw*rstd*g4.w + b4.w;
  if(xout) ((float4*)xout)[(size_t)b*256 + t] = y;
  if(xb16){
    ushort4 uu;
    uu.x = f2b(y.x); uu.y = f2b(y.y); uu.z = f2b(y.z); uu.w = f2b(y.w);
    ((ushort4*)xb16)[(size_t)b*256 + t] = uu;
  }
}

// ---------------------------------------------------------------------------
// skinny GEMM: part[ks,b,n] = A[16,Kslice] @ W[Kslice,N]   (A bf16)
__global__ __launch_bounds__(256) void g_skg(const float* __restrict__ W,
    const unsigned short* __restrict__ A, float* __restrict__ part,
    int N, int K, int KS){
  int nt = blockIdx.x, ks = blockIdx.y;
  int Ksl = K / KS, k0b = ks * Ksl, n0 = nt*64;
  int nc = Ksl >> 5;
  __shared__ unsigned short lt[2][64*40];
  int t = threadIdx.x, lane = t & 63, w = t >> 6;
  int k_loc = t >> 3, n_off = (t & 7)*8;
  const unsigned short* apb = A + (size_t)(lane & 15)*K + (lane >> 4)*8 + k0b;
  f32x4 acc = {0.f,0.f,0.f,0.f};
  float4 x0, x1;
  auto LD = [&](int c){
    const float* wp = W + (size_t)(k0b + c*32 + k_loc)*N + n0 + n_off;
    x0 = *(const float4*)wp;
    x1 = *(const float4*)(wp + 4);
  };
  auto ST = [&](int buf){
    unsigned short* p = &lt[buf][0];
    p[(n_off+0)*40 + k_loc] = f2b(x0.x);
    p[(n_off+1)*40 + k_loc] = f2b(x0.y);
    p[(n_off+2)*40 + k_loc] = f2b(x0.z);
    p[(n_off+3)*40 + k_loc] = f2b(x0.w);
    p[(n_off+4)*40 + k_loc] = f2b(x1.x);
    p[(n_off+5)*40 + k_loc] = f2b(x1.y);
    p[(n_off+6)*40 + k_loc] = f2b(x1.z);
    p[(n_off+7)*40 + k_loc] = f2b(x1.w);
  };
  LD(0); ST(0);
  for(int c=0; c<nc; ++c){
    if(c+1 < nc) LD(c+1);
    __syncthreads();
    bf16x8 af = *(const bf16x8*)(apb + c*32);
    bf16x8 bv = *(const bf16x8*)&lt[c&1][(w*16 + (lane & 15))*40 + (lane >> 4)*8];
    acc = mfma16(af, bv, acc);
    if(c+1 < nc) ST((c+1)&1);
  }
  int col = n0 + w*16 + (lane & 15);
  int r0 = (lane >> 4)*4;
  #pragma unroll
  for(int i=0;i<4;++i)
    part[ ((size_t)ks*16 + r0 + i)*(size_t)N + col ] = acc[i];
}

// ---------------------------------------------------------------------------
// skgf: FFN w2 GEMM with A = relu(sum_p fpart + b1) built in-register.
__global__ __launch_bounds__(256) void g_skgf(const float* __restrict__ W,
    const float* __restrict__ fpart, const float* __restrict__ b1,
    float* __restrict__ part){
  const int N = 1024, K = 4096, KS = 32;
  int nt = blockIdx.x, ks = blockIdx.y;
  int Ksl = K / KS, k0b = ks * Ksl, n0 = nt*64;
  int nc = Ksl >> 5;
  __shared__ unsigned short lt[2][64*40];
  int t = threadIdx.x, lane = t & 63, w = t >> 6;
  int k_loc = t >> 3, n_off = (t & 7)*8;
  int arow = lane & 15, akof = (lane >> 4)*8;
  f32x4 acc = {0.f,0.f,0.f,0.f};
  float4 x0, x1;
  auto LD = [&](int c){
    const float* wp = W + (size_t)(k0b + c*32 + k_loc)*N + n0 + n_off;
    x0 = *(const float4*)wp;
    x1 = *(const float4*)(wp + 4);
  };
  auto ST = [&](int buf){
    unsigned short* p = &lt[buf][0];
    p[(n_off+0)*40 + k_loc] = f2b(x0.x);
    p[(n_off+1)*40 + k_loc] = f2b(x0.y);
    p[(n_off+2)*40 + k_loc] = f2b(x0.z);
    p[(n_off+3)*40 + k_loc] = f2b(x0.w);
    p[(n_off+4)*40 + k_loc] = f2b(x1.x);
    p[(n_off+5)*40 + k_loc] = f2b(x1.y);
    p[(n_off+6)*40 + k_loc] = f2b(x1.z);
    p[(n_off+7)*40 + k_loc] = f2b(x1.w);
  };
  LD(0); ST(0);
  for(int c=0; c<nc; ++c){
    if(c+1 < nc) LD(c+1);
    int kk = k0b + c*32 + akof;
    float4 s0 = *(const float4*)(b1 + kk);
    float4 s1 = *(const float4*)(b1 + kk + 4);
    #pragma unroll
    for(int p=0; p<8; ++p){
      const float* fp = fpart + ((size_t)p*16 + arow)*4096 + kk;
      float4 p0 = *(const float4*)fp;
      float4 p1 = *(const float4*)(fp + 4);
      s0.x+=p0.x; s0.y+=p0.y; s0.z+=p0.z; s0.w+=p0.w;
      s1.x+=p1.x; s1.y+=p1.y; s1.z+=p1.z; s1.w+=p1.w;
    }
    bf16x8 af;
    af[0]=(short)f2b(fmaxf(s0.x,0.f)); af[1]=(short)f2b(fmaxf(s0.y,0.f));
    af[2]=(short)f2b(fmaxf(s0.z,0.f)); af[3]=(short)f2b(fmaxf(s0.w,0.f));
    af[4]=(short)f2b(fmaxf(s1.x,0.f)); af[5]=(short)f2b(fmaxf(s1.y,0.f));
    af[6]=(short)f2b(fmaxf(s1.z,0.f)); af[7]=(short)f2b(fmaxf(s1.w,0.f));
    __syncthreads();
    bf16x8 bv = *(const bf16x8*)&lt[c&1][(w*16 + (lane & 15))*40 + (lane >> 4)*8];
    acc = mfma16(af, bv, acc);
    if(c+1 < nc) ST((c+1)&1);
  }
  int col = n0 + w*16 + (lane & 15);
  int r0 = (lane >> 4)*4;
  #pragma unroll
  for(int i=0;i<4;++i)
    part[ ((size_t)ks*16 + r0 + i)*(size_t)N + col ] = acc[i];
}

// ---------------------------------------------------------------------------
extern "C" void kernel_launch(void* const* d_in, const int* in_sizes, int n_in,
                              void* d_out, int out_size, void* d_ws, size_t ws_size,
                              hipStream_t stream){
  const float* dec    = (const float*)d_in[0];
  const float* hist   = (const float*)d_in[1];
  const float* enc    = (const float*)d_in[2];
  const float* wq_s   = (const float*)d_in[3];
  const float* wk_s   = (const float*)d_in[4];
  const float* wv_s   = (const float*)d_in[5];
  const float* wo_s   = (const float*)d_in[6];
  const float* bo_s   = (const float*)d_in[7];
  const float* ln1_g  = (const float*)d_in[8];
  const float* ln1_b  = (const float*)d_in[9];
  const float* wq_c   = (const float*)d_in[10];
  const float* wk_c   = (const float*)d_in[11];
  const float* wv_c   = (const float*)d_in[12];
  const float* wo_c   = (const float*)d_in[13];
  const float* bo_c   = (const float*)d_in[14];
  const float* ln2_g  = (const float*)d_in[15];
  const float* ln2_b  = (const float*)d_in[16];
  const float* w1     = (const float*)d_in[17];
  const float* b1     = (const float*)d_in[18];
  const float* w2     = (const float*)d_in[19];
  const float* b2     = (const float*)d_in[20];
  const float* ln3_g  = (const float*)d_in[21];
  const float* ln3_b  = (const float*)d_in[22];

  float* out  = (float*)d_out;             // [16][1024]
  float* slf  = out + 16384;               // [16][16][2048]
  float* enco = out + 16384 + 524288;      // [16][16][2048]

  char* w = (char*)d_ws;
  float*          scr    = (float*)(w + 0x0000000);           // 2 MB
  unsigned short* partb  = (unsigned short*)(w + 0x0200000);  // 16 MB bf16
  float*          msum   = (float*)(w + 0x2200000);           // 64K
  unsigned short* qpb    = (unsigned short*)(w + 0x2240000);  // 512K
  unsigned short* ctxb   = (unsigned short*)(w + 0x22C0000);  // 512K
  float*          Qpart  = (float*)(w + 0x2340000);           // 512K
  float*          opart  = (float*)(w + 0x23C0000);           // 512K
  float*          x1     = (float*)(w + 0x2450000);           // 64K
  float*          x2     = (float*)(w + 0x2460000);           // 64K
  unsigned short* x2b    = (unsigned short*)(w + 0x2470000);  // 32K
  float*          gpart  = (float*)(w + 0x2500000);           // 1 MB
  float*          fpart  = (float*)(w + 0x2600000);           // 2 MB
  float*          g2part = (float*)(w + 0x2800000);           // 2 MB

  // ---- self attention ----
  g_qA   <<<dim3(8,16),  256, 0, stream>>>(dec, wq_s, Qpart);
  g_qB   <<<dim3(16,16), 256, 0, stream>>>(wk_s, Qpart, qpb);
  g_attn <<<512,  256, 0, stream>>>(hist, dec, qpb, scr, partb, msum, 2047);
  g_comb <<<dim3(4,256), 256, 0, stream>>>(msum, scr, partb, slf, ctxb);
  g_vproj<<<dim3(8,16),  256, 0, stream>>>(wv_s, ctxb, opart);
  g_skgo <<<dim3(16,16), 256, 0, stream>>>(wo_s, opart, gpart);
  g_ln   <<<16,   256, 0, stream>>>(gpart, 16, bo_s, dec, ln1_g, ln1_b, x1, (unsigned short*)0);

  // ---- cross attention ----
  g_qA   <<<dim3(8,16),  256, 0, stream>>>(x1, wq_c, Qpart);
  g_qB   <<<dim3(16,16), 256, 0, stream>>>(wk_c, Qpart, qpb);
  g_attn <<<512,  256, 0, stream>>>(enc, dec, qpb, scr, partb, msum, 2048);
  g_comb <<<dim3(4,256), 256, 0, stream>>>(msum, scr, partb, enco, ctxb);
  g_vproj<<<dim3(8,16),  256, 0, stream>>>(wv_c, ctxb, opart);
  g_skgo <<<dim3(16,16), 256, 0, stream>>>(wo_c, opart, gpart);
  g_ln   <<<16,   256, 0, stream>>>(gpart, 16, bo_c, x1, ln2_g, ln2_b, x2, x2b);

  // ---- FFN + final LN ----
  g_skg  <<<dim3(64,8),  256, 0, stream>>>(w1, x2b, fpart, 4096, 1024, 8);
  g_skgf <<<dim3(16,32), 256, 0, stream>>>(w2, fpart, b1, g2part);
  g_ln   <<<16,  256, 0, stream>>>(g2part, 32, b2, x2, ln3_g, ln3_b, out, (unsigned short*)0);
}